// Round 7
// baseline (255.438 us; speedup 1.0000x reference)
//
#include <hip/hip_runtime.h>
#include <hip/hip_bf16.h>

// CTC loss, fp32 in / fp32 out. T=1024, B=32, C=1024, L=128 fixed.
// R7: two changes to the fp64 meet-in-the-middle DP, both attacking the
//     ~250 cyc/step residual (theory: per-step __shfl_up = ds_bpermute puts
//     lgkmcnt on the serial chain; in-order retire drains the LDS prefetch
//     every step):
//     (a) DPP wave_shr:1 lane shift (pure VALU, no lgkmcnt) replaces shfl.
//     (b) blank emission factored out (divide-through): 7 f64 ops/step, no
//         eb load; correction sum(ln p_blank) added in combine.
#define T_DIM 1024
#define B_DIM 32
#define C_DIM 1024
#define L_DIM 128
#define S_DIM 257
#define CH    32          // timesteps per staged chunk

// ---- workspace layout (bytes) ----
#define WS_EPAIR   0                                  // [B][T][64] float2 = 16 MiB (ratios)
#define WS_LNB     (32u * 1024u * 64u * 8u)           // [B][T] float  (ln p_blank)
#define WS_ALPHA   (WS_LNB + 32u * 1024u * 4u)        // [B][264] double
#define WS_BETA    (WS_ALPHA + 32u * 264u * 8u)       // [B][264] double (257,258 = 0)
#define WS_KACC    (WS_BETA + 32u * 264u * 8u)        // [B][2] long long

// Lane shift down->up by 1 (lane l gets lane l-1's value; lane 0 gets 0).
__device__ __forceinline__ double lane_shr1_f64(double x) {
#if __has_builtin(__builtin_amdgcn_update_dpp)
    const int lo = __builtin_amdgcn_update_dpp(0, __double2loint(x), 0x138, 0xf, 0xf, true);
    const int hi = __builtin_amdgcn_update_dpp(0, __double2hiint(x), 0x138, 0xf, 0xf, true);
    return __hiloint2double(hi, lo);
#else
    double h = __shfl_up(x, 1, 64);
    return ((threadIdx.x & 63) == 0) ? 0.0 : h;
#endif
}

// ---------------- Kernel 1: log-softmax + emission ratios ----------------
// ratio(c) = p(c)/p(blank) = exp(logit_c - logit_0)  (lse cancels).
// lnb[b][t] = logit_0 - lse = ln p(blank)  (needs the lse reduction).
__global__ __launch_bounds__(256) void emit_kernel(const float* __restrict__ data,
                                                   const int* __restrict__ labels,
                                                   float2* __restrict__ epair,
                                                   float* __restrict__ lnblank) {
    const int wave = threadIdx.x >> 6;
    const int lane = threadIdx.x & 63;
    const int row = blockIdx.x * 4 + wave;           // row = t*B + b
    const int b = row & (B_DIM - 1);
    const int t = row >> 5;                          // B = 32

    const float4* d4 = (const float4*)(data + (size_t)row * C_DIM);
    float4 v[4];
    float m = -3.4e38f;
#pragma unroll
    for (int k = 0; k < 4; ++k) {
        v[k] = d4[lane + 64 * k];
        m = fmaxf(m, fmaxf(fmaxf(v[k].x, v[k].y), fmaxf(v[k].z, v[k].w)));
    }
#pragma unroll
    for (int off = 32; off >= 1; off >>= 1)
        m = fmaxf(m, __shfl_xor(m, off, 64));
    float s = 0.f;
#pragma unroll
    for (int k = 0; k < 4; ++k)
        s += __expf(v[k].x - m) + __expf(v[k].y - m) +
             __expf(v[k].z - m) + __expf(v[k].w - m);
#pragma unroll
    for (int off = 32; off >= 1; off >>= 1)
        s += __shfl_xor(s, off, 64);
    const float lse = m + __logf(s);

    const float* drow = data + (size_t)row * C_DIM;
    const float x0 = drow[0];
    const int2 cc = ((const int2*)(labels + b * L_DIM))[lane];   // labels 2l, 2l+1
    float2 pr;
    pr.x = __expf(drow[cc.x] - x0);
    pr.y = __expf(drow[cc.y] - x0);
    epair[((size_t)b * T_DIM + t) * 64 + lane] = pr;             // b-major rows
    if (lane == 0) lnblank[b * T_DIM + t] = x0 - lse;
}

// ---------------- Kernel 2: alpha/beta DP (fp64, blank-factored) ----------------
// grid = 64 blocks: b = blockIdx&31, dir = blockIdx>>5 (0=fwd alpha, 1=bwd beta).
// One wave per block. Lane l owns states 4l..4l+3 (lane 63 also 256).
// Per step: 2 DPP movs + 5 f64 add + 2 f64 fma + 2 f64 mul + 1 ds_read_b64.
__global__ __launch_bounds__(64, 1) void dp_kernel(const float2* __restrict__ epair,
                                                   const int* __restrict__ labels,
                                                   const int* __restrict__ label_length,
                                                   const int* __restrict__ data_length,
                                                   double* __restrict__ alphavec,
                                                   double* __restrict__ betavec,
                                                   long long* __restrict__ kaccs) {
    const int b   = blockIdx.x & (B_DIM - 1);
    const int dir = blockIdx.x >> 5;
    const int l = threadIdx.x;
    const int* lab = labels + b * L_DIM;
    const int len = label_length[b];
    const int dlen = data_length[b];
    const int m = dlen >> 1;          // split point: alpha(m-1) meets beta(m)

    __shared__ float2 ebuf[2][CH][64];   // 32 KiB double buffer

    const float2* eprow = epair + (size_t)b * T_DIM * 64;

    // Stage CH epair rows [trow0, trow0+CH) : 16 x (64 lanes x 16 B), 2 rows/instr.
    auto stage_chunk = [&](int cb, int trow0) {
#pragma unroll
        for (int i = 0; i < CH / 2; ++i)
            __builtin_amdgcn_global_load_lds(
                (const __attribute__((address_space(1))) void*)
                    ((const char*)(eprow + (size_t)(trow0 + 2 * i) * 64) + l * 16),
                (__attribute__((address_space(3))) void*)(&ebuf[cb][2 * i][0]), 16, 0, 0);
    };

    double a0 = 0.0, a1 = 0.0, a2 = 0.0, a3 = 0.0, a4 = 0.0;
    long long kacc = 0;

    // r1 multiplies state 4l+1, r3 multiplies state 4l+3 (fwd: ep.x/ep.y;
    // bwd reversed: ep.y/ep.x). Blank states are pure sums (eb divided out).
    double skip1d, skip3d;
    auto step = [&](double r1, double r3) {
        const double h = lane_shr1_f64(a3);          // alpha[4l-1] from lane l-1
        const double n0 = a0 + h;
        const double n1 = fma(skip1d, h, a1 + a0) * r1;
        const double n2 = a2 + a1;
        const double n3 = fma(skip3d, a1, a3 + a2) * r3;
        const double n4 = a4 + a3;
        a0 = n0; a1 = n1; a2 = n2; a3 = n3; a4 = n4;
    };

    auto renorm = [&]() {
        double mx = fmax(fmax(fmax(a0, a1), fmax(a2, a3)), a4);
        int hi = __double2hiint(mx);            // alphas >= 0: hi-word order = value order
#pragma unroll
        for (int off = 32; off >= 1; off >>= 1)
            hi = max(hi, __shfl_xor(hi, off, 64));
        const int ex = ((hi >> 20) & 0x7ff) - 1023;
        const double sc = __hiloint2double((1023 - ex) << 20, 0);   // 2^-ex
        a0 *= sc; a1 *= sc; a2 *= sc; a3 *= sc; a4 *= sc;
        kacc += ex;
    };

    if (dir == 0) {
        // ---------------- forward alpha: t = 0 .. m-1 ----------------
        const int2 cc = ((const int2*)lab)[l];                        // labels 2l, 2l+1
        skip1d = ((l > 0) && (cc.x != lab[2 * l - 1])) ? 1.0 : 0.0;
        skip3d = (cc.y != cc.x) ? 1.0 : 0.0;

        stage_chunk(0, 1);
        __builtin_amdgcn_s_waitcnt(0x0f70);     // vmcnt(0)

        {   // t = 0 init (divided by eb(0)): a'(0,0)=1, a'(0,1)=ratio
            const float2 ep0 = eprow[l];
            a0 = (l == 0) ? 1.0 : 0.0;
            a1 = (l == 0) ? (double)ep0.x : 0.0;
        }

        const int nsteps = m - 1;               // t = 1 .. m-1
        const int nch = (nsteps + CH - 1) / CH;
        for (int c = 0; c < nch; ++c) {
            const int cb = c & 1;
            const bool more = (c + 1 < nch);
            if (more) stage_chunk(cb ^ 1, 1 + CH * (c + 1));
            __builtin_amdgcn_sched_barrier(0);
            const int t0 = 1 + CH * c;
            if (t0 + CH <= m) {
                // full chunk: branch-free, distance-3 register rotation
                double r1R[4], r3R[4];
#pragma unroll
                for (int p = 0; p < 3; ++p) {
                    const float2 ep = ebuf[cb][p][l];
                    r1R[p] = (double)ep.x; r3R[p] = (double)ep.y;
                }
#pragma unroll
                for (int j = 0; j < CH; ++j) {
                    const int jn = (j + 3 < CH) ? (j + 3) : (CH - 1);
                    const float2 epn = ebuf[cb][jn][l];
                    step(r1R[j & 3], r3R[j & 3]);
                    r1R[(j + 3) & 3] = (double)epn.x;
                    r3R[(j + 3) & 3] = (double)epn.y;
                }
            } else {
                // tail chunk (once): predicated, plain LDS reads
#pragma unroll
                for (int j = 0; j < CH; ++j) {
                    if (t0 + j < m) {
                        const float2 ep = ebuf[cb][j][l];
                        step((double)ep.x, (double)ep.y);
                    }
                }
            }
            renorm();
            if (more) __builtin_amdgcn_s_waitcnt(0x0f70);
            __builtin_amdgcn_sched_barrier(0);
        }

        double* av = alphavec + b * 264;
        av[4 * l + 0] = a0; av[4 * l + 1] = a1;
        av[4 * l + 2] = a2; av[4 * l + 3] = a3;
        if (l == 63) av[256] = a4;
        if (l == 0) kaccs[2 * b + 0] = kacc;
    } else {
        // ---------------- backward beta: t = dlen-1 .. m (reversed states r=256-s) ----
        const int2 c2 = ((const int2*)lab)[63 - l];    // (lab[126-2l], lab[127-2l])
        const int labL = (l > 0) ? lab[128 - 2 * l] : -1;
        skip1d = ((l > 0) && (labL != c2.y)) ? 1.0 : 0.0;   // r=4l+1
        skip3d = (c2.y != c2.x) ? 1.0 : 0.0;                // r=4l+3

        stage_chunk(0, dlen - 1 - CH);          // rows [dlen-1-CH, dlen-2]
        __builtin_amdgcn_s_waitcnt(0x0f70);

        {   // init at t = dlen-1 (divided by eb): blank terminal -> 1, label -> ratio
            const float2 epi = eprow[(size_t)(dlen - 1) * 64 + (63 - l)];
            const int s0 = 256 - 4 * l;
            a0 = (s0 == 2 * len     || s0 == 2 * len - 1) ? 1.0 : 0.0;
            a1 = (s0 - 1 == 2 * len || s0 - 1 == 2 * len - 1) ? (double)epi.y : 0.0;
            a2 = (s0 - 2 == 2 * len || s0 - 2 == 2 * len - 1) ? 1.0 : 0.0;
            a3 = (s0 - 3 == 2 * len || s0 - 3 == 2 * len - 1) ? (double)epi.x : 0.0;
            a4 = 0.0;                            // lane63's r=256 is s=0, never terminal
        }

        const int nsteps = dlen - 1 - m;        // t = dlen-2 .. m
        const int nch = (nsteps + CH - 1) / CH;
        for (int c = 0; c < nch; ++c) {
            const int cb = c & 1;
            const bool more = (c + 1 < nch);
            const int thi = dlen - 2 - CH * c;
            const int tlo = thi - CH + 1;
            if (more) stage_chunk(cb ^ 1, tlo - CH);
            __builtin_amdgcn_sched_barrier(0);
            if (tlo >= m) {
                // full chunk: jj ascending = t descending; r1 = ep.y, r3 = ep.x
                double r1R[4], r3R[4];
#pragma unroll
                for (int p = 0; p < 3; ++p) {
                    const float2 ep = ebuf[cb][CH - 1 - p][63 - l];
                    r1R[p] = (double)ep.y; r3R[p] = (double)ep.x;
                }
#pragma unroll
                for (int jj = 0; jj < CH; ++jj) {
                    const int jnn = (jj + 3 < CH) ? (jj + 3) : (CH - 1);
                    const float2 epn = ebuf[cb][CH - 1 - jnn][63 - l];
                    step(r1R[jj & 3], r3R[jj & 3]);
                    r1R[(jj + 3) & 3] = (double)epn.y;
                    r3R[(jj + 3) & 3] = (double)epn.x;
                }
            } else {
                // tail chunk (once): predicated
#pragma unroll
                for (int jj = 0; jj < CH; ++jj) {
                    const int j = CH - 1 - jj;
                    const int t = tlo + j;
                    if (t >= m) {
                        const float2 ep = ebuf[cb][j][63 - l];
                        step((double)ep.y, (double)ep.x);
                    }
                }
            }
            renorm();
            if (more) __builtin_amdgcn_s_waitcnt(0x0f70);
            __builtin_amdgcn_sched_barrier(0);
        }

        double* bv = betavec + b * 264;               // natural s order
        bv[256 - 4 * l] = a0; bv[255 - 4 * l] = a1;
        bv[254 - 4 * l] = a2; bv[253 - 4 * l] = a3;
        if (l == 63) bv[0] = a4;
        if (l == 0) { bv[257] = 0.0; bv[258] = 0.0; kaccs[2 * b + 1] = kacc; }
    }
}

// ---------------- Kernel 3: combine + blank-log correction + mean ----------------
// Single block, 4 waves; wave w handles b = w, w+4, ..., w+28.
// loss_b = -( ln(sum_s alpha' T beta') + kacc*ln2 + sum_{t<dlen} ln p_blank(t) )
__global__ __launch_bounds__(256) void combine_kernel(const double* __restrict__ alphavec,
                                                      const double* __restrict__ betavec,
                                                      const long long* __restrict__ kaccs,
                                                      const int* __restrict__ labels,
                                                      const int* __restrict__ data_length,
                                                      const float* __restrict__ lnblank,
                                                      float* __restrict__ out) {
    const int wave = threadIdx.x >> 6;
    const int l = threadIdx.x & 63;
    float acc = 0.f;

    for (int b = wave; b < B_DIM; b += 4) {
        const double* A = alphavec + b * 264;
        const double* Bv = betavec + b * 264;
        const int* lab = labels + b * L_DIM;
        const int dlen = data_length[b];

        const double a0 = A[4 * l], a1 = A[4 * l + 1], a2 = A[4 * l + 2], a3 = A[4 * l + 3];
        const double b0 = Bv[4 * l], b1 = Bv[4 * l + 1], b2 = Bv[4 * l + 2];
        const double b3 = Bv[4 * l + 3], b4 = Bv[4 * l + 4], b5 = Bv[4 * l + 5];
        const double sk1 = (lab[2 * l + 1] != lab[2 * l]) ? 1.0 : 0.0;        // into 4l+3
        const int labn = (l < 63) ? lab[2 * l + 2] : -1;
        const double sk3 = ((l < 63) && (labn != lab[2 * l + 1])) ? 1.0 : 0.0; // into 4l+5

        double s = a0 * (b0 + b1)
                 + a1 * (b1 + b2 + sk1 * b3)
                 + a2 * (b2 + b3)
                 + a3 * (b3 + b4 + sk3 * b5);
        if (l == 63) s += A[256] * Bv[256];

        // blank-log correction
        const float* lnb = lnblank + b * T_DIM;
        double slnb = 0.0;
        for (int t = l; t < dlen; t += 64) slnb += (double)lnb[t];

#pragma unroll
        for (int off = 32; off >= 1; off >>= 1) {
            s    += __shfl_xor(s, off, 64);
            slnb += __shfl_xor(slnb, off, 64);
        }

        if (l == 0) {
            const long long k = kaccs[2 * b] + kaccs[2 * b + 1];
            const long long vb = __double_as_longlong(s);
            const int ve = (int)((vb >> 52) & 0x7ff) - 1023;
            const double mant = __longlong_as_double(
                (vb & 0x000FFFFFFFFFFFFFLL) | (1023LL << 52));        // [1,2)
            const double l2 = (double)__log2f((float)mant) + (double)ve + (double)k;
            acc += (float)(-(l2 * 0.6931471805599453 + slnb));
        }
    }

    __shared__ float part[4];
    if (l == 0) part[wave] = acc;
    __syncthreads();
    if (threadIdx.x == 0)
        out[0] = (part[0] + part[1] + part[2] + part[3]) * (1.0f / B_DIM);
}

extern "C" void kernel_launch(void* const* d_in, const int* in_sizes, int n_in,
                              void* d_out, int out_size, void* d_ws, size_t ws_size,
                              hipStream_t stream) {
    const int*   labels       = (const int*)d_in[0];
    const float* data         = (const float*)d_in[1];
    const int*   label_length = (const int*)d_in[2];
    const int*   data_length  = (const int*)d_in[3];
    float*       out          = (float*)d_out;

    char* ws = (char*)d_ws;
    float2*    epair    = (float2*)(ws + WS_EPAIR);
    float*     lnblank  = (float*)(ws + WS_LNB);
    double*    alphavec = (double*)(ws + WS_ALPHA);
    double*    betavec  = (double*)(ws + WS_BETA);
    long long* kaccs    = (long long*)(ws + WS_KACC);

    const int rows = T_DIM * B_DIM;
    emit_kernel<<<rows / 4, 256, 0, stream>>>(data, labels, epair, lnblank);
    dp_kernel<<<2 * B_DIM, 64, 0, stream>>>(epair, labels, label_length,
                                            data_length, alphavec, betavec, kaccs);
    combine_kernel<<<1, 256, 0, stream>>>(alphavec, betavec, kaccs, labels,
                                          data_length, lnblank, out);
}